// Round 5
// baseline (203.303 us; speedup 1.0000x reference)
//
#include <hip/hip_runtime.h>
#include <hip/hip_bf16.h>
#include <math.h>

// ---------- helpers ----------
typedef short bf16x8 __attribute__((ext_vector_type(8)));
typedef float f32x4 __attribute__((ext_vector_type(4)));

__device__ __forceinline__ float bf2f(unsigned short u) {
    return __uint_as_float(((unsigned int)u) << 16);
}
__device__ __forceinline__ unsigned short f2bf(float f) {
    unsigned int u = __float_as_uint(f);
    u = (u + 0x7FFFu + ((u >> 16) & 1u)) >> 16;
    return (unsigned short)u;
}
__device__ __forceinline__ unsigned int pk2bf(float a, float b) {
    __hip_bfloat162 u = __float22bfloat162_rn(make_float2(a, b));
    return *(unsigned int*)&u;
}

// async global->LDS, 16B per lane; LDS dest = wave-uniform base + lane*16
#define ASYNC16(gp, lp)                                                        \
    __builtin_amdgcn_global_load_lds(                                          \
        (const __attribute__((address_space(1))) unsigned int*)(gp),           \
        (__attribute__((address_space(3))) unsigned int*)(lp), 16, 0, 0)

// ---------- prep: fp32 [K][N] -> bf16 [N][K] (B^T layout for GEMM) ----------
__global__ __launch_bounds__(256) void transpose_cast_kernel(const float* __restrict__ in,
                                                             unsigned short* __restrict__ out,
                                                             int K, int N) {
    __shared__ float tile[32][33];
    int k0 = blockIdx.x * 32, n0 = blockIdx.y * 32;
    int tx = threadIdx.x & 31, ty = threadIdx.x >> 5;
    #pragma unroll
    for (int i = ty; i < 32; i += 8)
        tile[i][tx] = in[(size_t)(k0 + i) * N + (n0 + tx)];
    __syncthreads();
    #pragma unroll
    for (int i = ty; i < 32; i += 8)
        out[(size_t)(n0 + i) * K + (k0 + tx)] = f2bf(tile[tx][i]);
}

// ---------- prep: bf16 k-half of qkb [token][feature] -> kT [b*1024+f][token] ----------
__global__ __launch_bounds__(256) void ktrans_kernel(const unsigned short* __restrict__ qkb,
                                                     unsigned short* __restrict__ kT) {
    __shared__ unsigned short tl[64][68];
    const int b = blockIdx.z;
    const int tok0 = blockIdx.x * 64;
    const int f0 = blockIdx.y * 64;
    const int r = threadIdx.x >> 4;        // 0..15
    const int c = (threadIdx.x & 15) * 4;  // 0..60
    #pragma unroll
    for (int i = 0; i < 4; ++i) {
        const int rr = r + 16 * i;
        ushort4 v = *(const ushort4*)(qkb + ((size_t)(b * 2048 + tok0 + rr)) * 2048 + 1024 + f0 + c);
        *(ushort4*)&tl[rr][c] = v;
    }
    __syncthreads();
    #pragma unroll
    for (int i = 0; i < 4; ++i) {
        const int fr = r + 16 * i;
        ushort4 v;
        v.x = tl[c + 0][fr]; v.y = tl[c + 1][fr]; v.z = tl[c + 2][fr]; v.w = tl[c + 3][fr];
        *(ushort4*)(kT + ((size_t)(b * 1024 + f0 + fr)) * 2048 + tok0 + c) = v;
    }
}

// ---------- 128x128 MFMA GEMM; A either bf16 (ASYNC16) or fp32 (fused cast) ----------
template <bool STORE_BF16, bool A_FP32>
__global__ __launch_bounds__(256) void gemm128_kernel(const void* __restrict__ Av,
                                                      const unsigned short* __restrict__ Bt,
                                                      void* __restrict__ C,
                                                      int K, int lda, int ldb, int ldc) {
    constexpr int ASTR = A_FP32 ? 40 : 32;  // padded stride for ds_write path
    __shared__ unsigned short As[128 * ASTR];
    __shared__ unsigned short Bs[128 * 32];
    const int tid = threadIdx.x;
    const int wave = tid >> 6;
    const int lane = tid & 63;
    const int quad = lane >> 4;
    const int col  = lane & 15;
    const int wm = (wave >> 1) * 64;
    const int wn = (wave & 1) * 64;
    const int m0 = blockIdx.x * 128, n0 = blockIdx.y * 128;

    f32x4 acc[4][4];
    #pragma unroll
    for (int i = 0; i < 4; ++i)
        #pragma unroll
        for (int j = 0; j < 4; ++j) { acc[i][j][0] = 0.f; acc[i][j][1] = 0.f; acc[i][j][2] = 0.f; acc[i][j][3] = 0.f; }

    const int srow = tid >> 2;
    const int skc  = (tid & 3) * 8;
    const int frow = tid >> 1;          // fp32-A path: 0..127
    const int fcol = (tid & 1) * 16;    // 0 / 16

    for (int k0 = 0; k0 < K; k0 += 32) {
        __syncthreads();
        if (A_FP32) {
            const float* gx = (const float*)Av + (size_t)(m0 + frow) * lda + k0 + fcol;
            float4 f0 = *(const float4*)(gx);
            float4 f1 = *(const float4*)(gx + 4);
            float4 f2 = *(const float4*)(gx + 8);
            float4 f3 = *(const float4*)(gx + 12);
            uint4 w0 = make_uint4(pk2bf(f0.x, f0.y), pk2bf(f0.z, f0.w),
                                  pk2bf(f1.x, f1.y), pk2bf(f1.z, f1.w));
            uint4 w1 = make_uint4(pk2bf(f2.x, f2.y), pk2bf(f2.z, f2.w),
                                  pk2bf(f3.x, f3.y), pk2bf(f3.z, f3.w));
            *(uint4*)&As[frow * ASTR + fcol]     = w0;
            *(uint4*)&As[frow * ASTR + fcol + 8] = w1;
        } else {
            const unsigned short* ga = (const unsigned short*)Av + (size_t)(m0 + srow) * lda + k0 + skc;
            ASYNC16(ga,            &As[wave * 512]);
            ASYNC16(ga + 64 * lda, &As[2048 + wave * 512]);
        }
        const unsigned short* gb = Bt + (size_t)(n0 + srow) * ldb + k0 + skc;
        ASYNC16(gb,            &Bs[wave * 512]);
        ASYNC16(gb + 64 * ldb, &Bs[2048 + wave * 512]);
        __syncthreads();  // drains vmcnt + lgkmcnt -> LDS visible

        bf16x8 af[4], bf[4];
        #pragma unroll
        for (int mf = 0; mf < 4; ++mf)
            af[mf] = *(const bf16x8*)&As[(wm + mf * 16 + col) * ASTR + quad * 8];
        #pragma unroll
        for (int nf = 0; nf < 4; ++nf)
            bf[nf] = *(const bf16x8*)&Bs[(wn + nf * 16 + col) * 32 + quad * 8];
        #pragma unroll
        for (int mf = 0; mf < 4; ++mf)
            #pragma unroll
            for (int nf = 0; nf < 4; ++nf)
                acc[mf][nf] = __builtin_amdgcn_mfma_f32_16x16x32_bf16(af[mf], bf[nf], acc[mf][nf], 0, 0, 0);
    }

    #pragma unroll
    for (int mf = 0; mf < 4; ++mf) {
        const int row0 = m0 + wm + mf * 16 + quad * 4;
        #pragma unroll
        for (int nf = 0; nf < 4; ++nf) {
            const int cc = n0 + wn + nf * 16 + col;
            #pragma unroll
            for (int r = 0; r < 4; ++r) {
                if (STORE_BF16)
                    ((unsigned short*)C)[(size_t)(row0 + r) * ldc + cc] = f2bf(acc[mf][nf][r]);
                else
                    ((float*)C)[(size_t)(row0 + r) * ldc + cc] = acc[mf][nf][r];
            }
        }
    }
}

// ---------- MFMA flash attention v4: 32-query blocks for occupancy ----------
// Block = 2 waves = 32 queries of one (b,h); grid (32 bh, 64 qtiles) = 2048
// blocks -> 8 blocks/CU (LDS caps at 7). Same max-free softmax (bias -16 in
// accumulator init) and XOR-swizzled ASYNC16 staging as v3.
#define LDK 72  // Ps row stride (shorts)

__global__ __launch_bounds__(128) void attn_v4_kernel(const unsigned short* __restrict__ qkb,
                                                      const unsigned short* __restrict__ kT,
                                                      unsigned short* __restrict__ aout) {
    __shared__ unsigned short Kn[64 * 64];      // [key][dim], swizzled
    __shared__ unsigned short Kt[64 * 64];      // [dim][key], swizzled
    __shared__ unsigned short Ps[2][16 * LDK];  // per-wave P: [query][key], padded

    const int bh = blockIdx.x;
    const int b = bh >> 4, h = bh & 15;
    const int qt = 63 - (int)blockIdx.y;        // heavy tiles dispatch first
    const int tid = threadIdx.x;
    const int wave = tid >> 6, lane = tid & 63, quad = lane >> 4, col = lane & 15;
    const int Q0 = qt * 32;

    // Q frags (B-operand of S^T mfma), fold beta*log2(e) so exp -> exp2
    bf16x8 qa0, qa1;
    {
        const unsigned short* qp =
            qkb + ((size_t)(b * 2048 + Q0 + wave * 16 + col)) * 2048 + h * 64;
        bf16x8 r0 = *(const bf16x8*)(qp + quad * 8);
        bf16x8 r1 = *(const bf16x8*)(qp + 32 + quad * 8);
        const float sc = 0.125f * 1.44269504088896f;
        #pragma unroll
        for (int i = 0; i < 8; ++i) {
            qa0[i] = (short)f2bf(bf2f((unsigned short)r0[i]) * sc);
            qa1[i] = (short)f2bf(bf2f((unsigned short)r1[i]) * sc);
        }
    }

    f32x4 accO[4];  // O[q=quad*4+r][d=t*16+col]
    #pragma unroll
    for (int t = 0; t < 4; ++t) { accO[t][0] = 0.f; accO[t][1] = 0.f; accO[t][2] = 0.f; accO[t][3] = 0.f; }
    float lsum = 0.f;  // per-lane partial denominator (x 2^-16)

    // staging: wave stages rows wave*32..+31 in 4 groups of 8; lane covers row
    // r8=lane/8 of a group, global chunk (lane%8)^r8 -> swizzle slot c^(r&7)
    const int r8 = lane >> 3;
    const int c8 = (lane & 7) ^ r8;
    const unsigned short* knp =
        qkb + ((size_t)(b * 2048 + wave * 32 + r8)) * 2048 + 1024 + h * 64 + c8 * 8;
    const unsigned short* ktp = kT + ((size_t)(bh * 64 + wave * 32 + r8)) * 2048 + c8 * 8;
    unsigned short* const knl = &Kn[(wave * 32) * 64];
    unsigned short* const ktl = &Kt[(wave * 32) * 64];

    const int jtd = qt >> 1;                    // diagonal 64-key tile index
    const int qoff = (qt & 1) * 32 + wave * 16; // query offset within diag tile
    const int tdiag = qoff >> 4;                // frag index holding the diagonal

    for (int jt = 0; jt <= jtd; ++jt) {
        __syncthreads();                        // protect prior iter's Kn/Kt reads
        #pragma unroll
        for (int g = 0; g < 4; ++g) {
            ASYNC16(knp + g * 8 * 2048, knl + g * 8 * 64);
            ASYNC16(ktp + g * 8 * 2048, ktl + g * 8 * 64);
        }
        knp += 64 * 2048;
        ktp += 64;
        __syncthreads();                        // drains vmcnt -> LDS visible

        const bool diag = (jt == jtd);
        const int tmax = diag ? tdiag : 3;

        float ls = 0.f;
        unsigned int pw[4][2];
        #pragma unroll
        for (int t = 0; t < 4; ++t) {
            if (t <= tmax) {
                const int row = (t * 16 + col) * 64;
                const int sw = col & 7;
                bf16x8 ka0 = *(const bf16x8*)&Kn[row + (quad ^ sw) * 8];
                bf16x8 ka1 = *(const bf16x8*)&Kn[row + ((4 + quad) ^ sw) * 8];
                f32x4 c = {-16.f, -16.f, -16.f, -16.f};   // exp2 bias, free
                c = __builtin_amdgcn_mfma_f32_16x16x32_bf16(ka0, qa0, c, 0, 0, 0);
                c = __builtin_amdgcn_mfma_f32_16x16x32_bf16(ka1, qa1, c, 0, 0, 0);
                if (diag && t == tdiag) {
                    #pragma unroll
                    for (int r = 0; r < 4; ++r)
                        if (quad * 4 + r > col) c[r] = -1e30f;   // exp2 -> 0
                }
                const float p0 = exp2f(c[0]);
                const float p1 = exp2f(c[1]);
                const float p2 = exp2f(c[2]);
                const float p3 = exp2f(c[3]);
                ls += (p0 + p1) + (p2 + p3);
                pw[t][0] = pk2bf(p0, p1);
                pw[t][1] = pk2bf(p2, p3);
            } else {
                pw[t][0] = 0u; pw[t][1] = 0u;
            }
        }
        lsum += ls;

        // P -> LDS [query][key] (b64, conflict-free), read back as A-frags
        unsigned short* psb = &Ps[wave][col * LDK];
        #pragma unroll
        for (int t = 0; t < 4; ++t)
            *(uint2*)(psb + t * 16 + quad * 4) = make_uint2(pw[t][0], pw[t][1]);

        bf16x8 pa0 = *(const bf16x8*)(psb + quad * 8);        // keys 0..31
        bf16x8 pa1 = *(const bf16x8*)(psb + 32 + quad * 8);   // keys 32..63
        const bool hi = !(diag && tdiag < 2);                 // keys 32..63 all masked?

        #pragma unroll
        for (int t = 0; t < 4; ++t) {
            const int row = (t * 16 + col) * 64;
            const int sw = col & 7;
            bf16x8 vb0 = *(const bf16x8*)&Kt[row + (quad ^ sw) * 8];
            accO[t] = __builtin_amdgcn_mfma_f32_16x16x32_bf16(pa0, vb0, accO[t], 0, 0, 0);
            if (hi) {
                bf16x8 vb1 = *(const bf16x8*)&Kt[row + ((4 + quad) ^ sw) * 8];
                accO[t] = __builtin_amdgcn_mfma_f32_16x16x32_bf16(pa1, vb1, accO[t], 0, 0, 0);
            }
        }
    }

    // epilogue: reduce l across quads once, then O /= l
    lsum += __shfl_xor(lsum, 16);
    lsum += __shfl_xor(lsum, 32);
    #pragma unroll
    for (int r = 0; r < 4; ++r) {
        const float lr = __shfl(lsum, (lane & 48) | (quad * 4 + r));
        const float inv = 1.f / lr;
        const size_t row = (size_t)b * 2048 + Q0 + wave * 16 + quad * 4 + r;
        unsigned short* op = aout + row * 1024 + h * 64;
        op[col]      = f2bf(accO[0][r] * inv);
        op[16 + col] = f2bf(accO[1][r] * inv);
        op[32 + col] = f2bf(accO[2][r] * inv);
        op[48 + col] = f2bf(accO[3][r] * inv);
    }
}

// ---------- launch ----------
extern "C" void kernel_launch(void* const* d_in, const int* in_sizes, int n_in,
                              void* d_out, int out_size, void* d_ws, size_t ws_size,
                              hipStream_t stream) {
    (void)in_sizes; (void)n_in; (void)out_size; (void)ws_size;
    const float* x    = (const float*)d_in[0];   // [2,2048,1024]
    const float* Wqk  = (const float*)d_in[1];   // [1024,2048]
    const float* Wout = (const float*)d_in[2];   // [1024,1024]
    float* out = (float*)d_out;                  // [2,2048,1024] fp32

    unsigned short* kT     = (unsigned short*)d_ws;            // [2048][2048] (8MB)
    unsigned short* Wqk_t  = kT     + (size_t)4096 * 1024;     // [2048][1024]
    unsigned short* Wout_t = Wqk_t  + (size_t)2048 * 1024;     // [1024][1024]
    unsigned short* qkb    = Wout_t + (size_t)1024 * 1024;     // [4096][2048]
    unsigned short* aoutb  = qkb    + (size_t)4096 * 2048;     // [4096][1024]

    transpose_cast_kernel<<<dim3(32, 64), dim3(256), 0, stream>>>(Wqk, Wqk_t, 1024, 2048);
    transpose_cast_kernel<<<dim3(32, 32), dim3(256), 0, stream>>>(Wout, Wout_t, 1024, 1024);

    // qk = x @ W_qk -> bf16 [4096][2048]  (fp32 A cast fused into staging)
    gemm128_kernel<true, true><<<dim3(32, 16), dim3(256), 0, stream>>>(
        (const void*)x, Wqk_t, (void*)qkb, 1024, 1024, 1024, 2048);

    // K^T per batch: [b*1024+f][token]
    ktrans_kernel<<<dim3(32, 16, 2), dim3(256), 0, stream>>>(qkb, kT);

    // causal MFMA flash attention -> bf16 [4096][1024]
    attn_v4_kernel<<<dim3(32, 64), dim3(128), 0, stream>>>(qkb, kT, aoutb);

    // out = attn_out @ W_out -> fp32
    gemm128_kernel<false, false><<<dim3(32, 8), dim3(256), 0, stream>>>(
        (const void*)aoutb, Wout_t, (void*)out, 1024, 1024, 1024, 1024);
}

// Round 6
// 194.830 us; speedup vs baseline: 1.0435x; 1.0435x over previous
//
#include <hip/hip_runtime.h>
#include <hip/hip_bf16.h>
#include <math.h>

// ---------- helpers ----------
typedef short bf16x8 __attribute__((ext_vector_type(8)));
typedef float f32x4 __attribute__((ext_vector_type(4)));

__device__ __forceinline__ float bf2f(unsigned short u) {
    return __uint_as_float(((unsigned int)u) << 16);
}
__device__ __forceinline__ unsigned short f2bf(float f) {
    unsigned int u = __float_as_uint(f);
    u = (u + 0x7FFFu + ((u >> 16) & 1u)) >> 16;
    return (unsigned short)u;
}
__device__ __forceinline__ unsigned int pk2bf(float a, float b) {
    __hip_bfloat162 u = __float22bfloat162_rn(make_float2(a, b));
    return *(unsigned int*)&u;
}

// async global->LDS, 16B per lane; LDS dest = wave-uniform base + lane*16
#define ASYNC16(gp, lp)                                                        \
    __builtin_amdgcn_global_load_lds(                                          \
        (const __attribute__((address_space(1))) unsigned int*)(gp),           \
        (__attribute__((address_space(3))) unsigned int*)(lp), 16, 0, 0)

// ---------- prep: fp32 -> bf16 cast ----------
__global__ __launch_bounds__(256) void cast_x_kernel(const float* __restrict__ in,
                                                     unsigned short* __restrict__ out, int n) {
    int i = (blockIdx.x * 256 + threadIdx.x) * 8;
    if (i >= n) return;
    float4 a = *(const float4*)(in + i);
    float4 b = *(const float4*)(in + i + 4);
    bf16x8 v;
    v[0] = (short)f2bf(a.x); v[1] = (short)f2bf(a.y); v[2] = (short)f2bf(a.z); v[3] = (short)f2bf(a.w);
    v[4] = (short)f2bf(b.x); v[5] = (short)f2bf(b.y); v[6] = (short)f2bf(b.z); v[7] = (short)f2bf(b.w);
    *(bf16x8*)(out + i) = v;
}

// ---------- prep: fp32 [K][N] -> bf16 [N][K] (B^T layout for GEMM) ----------
__global__ __launch_bounds__(256) void transpose_cast_kernel(const float* __restrict__ in,
                                                             unsigned short* __restrict__ out,
                                                             int K, int N) {
    __shared__ float tile[32][33];
    int k0 = blockIdx.x * 32, n0 = blockIdx.y * 32;
    int tx = threadIdx.x & 31, ty = threadIdx.x >> 5;
    #pragma unroll
    for (int i = ty; i < 32; i += 8)
        tile[i][tx] = in[(size_t)(k0 + i) * N + (n0 + tx)];
    __syncthreads();
    #pragma unroll
    for (int i = ty; i < 32; i += 8)
        out[(size_t)(n0 + i) * K + (k0 + tx)] = f2bf(tile[tx][i]);
}

// ---------- prep: bf16 k-half of qkb [token][feature] -> kT [b*1024+f][token] ----------
__global__ __launch_bounds__(256) void ktrans_kernel(const unsigned short* __restrict__ qkb,
                                                     unsigned short* __restrict__ kT) {
    __shared__ unsigned short tl[64][68];
    const int b = blockIdx.z;
    const int tok0 = blockIdx.x * 64;
    const int f0 = blockIdx.y * 64;
    const int r = threadIdx.x >> 4;        // 0..15
    const int c = (threadIdx.x & 15) * 4;  // 0..60
    #pragma unroll
    for (int i = 0; i < 4; ++i) {
        const int rr = r + 16 * i;
        ushort4 v = *(const ushort4*)(qkb + ((size_t)(b * 2048 + tok0 + rr)) * 2048 + 1024 + f0 + c);
        *(ushort4*)&tl[rr][c] = v;
    }
    __syncthreads();
    #pragma unroll
    for (int i = 0; i < 4; ++i) {
        const int fr = r + 16 * i;
        ushort4 v;
        v.x = tl[c + 0][fr]; v.y = tl[c + 1][fr]; v.z = tl[c + 2][fr]; v.w = tl[c + 3][fr];
        *(ushort4*)(kT + ((size_t)(b * 1024 + f0 + fr)) * 2048 + tok0 + c) = v;
    }
}

// ---------- m97-style 128x128 MFMA GEMM, global_load_lds staging ----------
template <bool STORE_BF16>
__global__ __launch_bounds__(256) void gemm128_kernel(const unsigned short* __restrict__ A,
                                                      const unsigned short* __restrict__ Bt,
                                                      void* __restrict__ C,
                                                      int K, int lda, int ldb, int ldc) {
    __shared__ unsigned short As[128 * 32];
    __shared__ unsigned short Bs[128 * 32];
    const int tid = threadIdx.x;
    const int wave = tid >> 6;
    const int lane = tid & 63;
    const int quad = lane >> 4;
    const int col  = lane & 15;
    const int wm = (wave >> 1) * 64;
    const int wn = (wave & 1) * 64;
    const int m0 = blockIdx.x * 128, n0 = blockIdx.y * 128;

    f32x4 acc[4][4];
    #pragma unroll
    for (int i = 0; i < 4; ++i)
        #pragma unroll
        for (int j = 0; j < 4; ++j) { acc[i][j][0] = 0.f; acc[i][j][1] = 0.f; acc[i][j][2] = 0.f; acc[i][j][3] = 0.f; }

    const int srow = tid >> 2;
    const int skc  = (tid & 3) * 8;

    for (int k0 = 0; k0 < K; k0 += 32) {
        __syncthreads();
        const unsigned short* ga = A  + (size_t)(m0 + srow) * lda + k0 + skc;
        const unsigned short* gb = Bt + (size_t)(n0 + srow) * ldb + k0 + skc;
        ASYNC16(ga,            &As[wave * 512]);
        ASYNC16(ga + 64 * lda, &As[2048 + wave * 512]);
        ASYNC16(gb,            &Bs[wave * 512]);
        ASYNC16(gb + 64 * ldb, &Bs[2048 + wave * 512]);
        __syncthreads();

        bf16x8 af[4], bf[4];
        #pragma unroll
        for (int mf = 0; mf < 4; ++mf)
            af[mf] = *(const bf16x8*)&As[(wm + mf * 16 + col) * 32 + quad * 8];
        #pragma unroll
        for (int nf = 0; nf < 4; ++nf)
            bf[nf] = *(const bf16x8*)&Bs[(wn + nf * 16 + col) * 32 + quad * 8];
        #pragma unroll
        for (int mf = 0; mf < 4; ++mf)
            #pragma unroll
            for (int nf = 0; nf < 4; ++nf)
                acc[mf][nf] = __builtin_amdgcn_mfma_f32_16x16x32_bf16(af[mf], bf[nf], acc[mf][nf], 0, 0, 0);
    }

    #pragma unroll
    for (int mf = 0; mf < 4; ++mf) {
        const int row0 = m0 + wm + mf * 16 + quad * 4;
        #pragma unroll
        for (int nf = 0; nf < 4; ++nf) {
            const int cc = n0 + wn + nf * 16 + col;
            #pragma unroll
            for (int r = 0; r < 4; ++r) {
                if (STORE_BF16)
                    ((unsigned short*)C)[(size_t)(row0 + r) * ldc + cc] = f2bf(acc[mf][nf][r]);
                else
                    ((float*)C)[(size_t)(row0 + r) * ldc + cc] = acc[mf][nf][r];
            }
        }
    }
}

// ---------- MFMA flash attention v5: software-pipelined K-loop ----------
// v3 structure (4 waves = 64 queries, max-free softmax, XOR-swizzled staging)
// + double-buffered Kn/Kt with AITER-style fine-grained vmcnt:
//   B1 (raw s_barrier, no drain) -> issue tile jt+1 async -> s_waitcnt vmcnt(4)
//   (own tile-jt loads landed, jt+1 stays in flight) -> B2 (raw) -> compute.
// Neither barrier drains vmcnt to 0, so prefetch overlaps compute.
#define LDK 72  // Ps row stride (shorts)

__global__ __launch_bounds__(256) void attn_v5_kernel(const unsigned short* __restrict__ qkb,
                                                      const unsigned short* __restrict__ kT,
                                                      unsigned short* __restrict__ aout) {
    __shared__ unsigned short Kbuf[2][2][64 * 64];  // [buf][Kn|Kt][key/dim][64], swizzled
    __shared__ unsigned short Ps[4][16 * LDK];      // per-wave P: [query][key], padded

    const int bh = blockIdx.x;
    const int b = bh >> 4, h = bh & 15;
    const int qtile = 31 - (int)blockIdx.y;         // heavy tiles dispatch first
    const int tid = threadIdx.x;
    const int wave = tid >> 6, lane = tid & 63, quad = lane >> 4, col = lane & 15;

    // Q frags (B-operand of S^T mfma), fold beta*log2(e) so exp -> exp2
    bf16x8 qa0, qa1;
    {
        const unsigned short* qp =
            qkb + ((size_t)(b * 2048 + qtile * 64 + wave * 16 + col)) * 2048 + h * 64;
        bf16x8 r0 = *(const bf16x8*)(qp + quad * 8);
        bf16x8 r1 = *(const bf16x8*)(qp + 32 + quad * 8);
        const float sc = 0.125f * 1.44269504088896f;
        #pragma unroll
        for (int i = 0; i < 8; ++i) {
            qa0[i] = (short)f2bf(bf2f((unsigned short)r0[i]) * sc);
            qa1[i] = (short)f2bf(bf2f((unsigned short)r1[i]) * sc);
        }
    }

    f32x4 accO[4];  // O[q=quad*4+r][d=t*16+col]
    #pragma unroll
    for (int t = 0; t < 4; ++t) { accO[t][0] = 0.f; accO[t][1] = 0.f; accO[t][2] = 0.f; accO[t][3] = 0.f; }
    float lsum = 0.f;  // per-lane partial denominator (x 2^-16)

    // staging: lane covers row r8=lane/8 of an 8-row group, global chunk (lane%8)^r8
    const int r8 = lane >> 3;
    const int c8 = (lane & 7) ^ r8;
    const unsigned short* knp =
        qkb + ((size_t)(b * 2048 + wave * 16 + r8)) * 2048 + 1024 + h * 64 + c8 * 8;
    const unsigned short* ktp = kT + ((size_t)(bh * 64 + wave * 16 + r8)) * 2048 + c8 * 8;

    auto issue = [&](int jt, int p) {
        const unsigned short* kn = knp + (size_t)jt * 64 * 2048;
        const unsigned short* kt = ktp + jt * 64;
        unsigned short* knl = &Kbuf[p][0][(wave * 16) * 64];
        unsigned short* ktl = &Kbuf[p][1][(wave * 16) * 64];
        ASYNC16(kn,            knl);
        ASYNC16(kn + 8 * 2048, knl + 8 * 64);
        ASYNC16(kt,            ktl);
        ASYNC16(kt + 8 * 2048, ktl + 8 * 64);
    };

    issue(0, 0);  // prologue: tile 0 -> buf 0

    for (int jt = 0; jt <= qtile; ++jt) {
        const int cur = jt & 1;
        __builtin_amdgcn_s_barrier();            // B1: all waves done reading buf[cur^1]
        if (jt < qtile) issue(jt + 1, cur ^ 1);  // prefetch next tile (4 async, in flight)
        if (jt < qtile) __builtin_amdgcn_s_waitcnt(0xF74);  // vmcnt(4): own tile-jt landed
        else            __builtin_amdgcn_s_waitcnt(0xF70);  // vmcnt(0): last tile
        __builtin_amdgcn_s_barrier();            // B2: everyone's tile-jt landed
        __asm__ volatile("" ::: "memory");       // fence compiler reordering across B2

        const unsigned short* Knc = &Kbuf[cur][0][0];
        const unsigned short* Ktc = &Kbuf[cur][1][0];

        const bool diag = (jt == qtile);
        const int tmax = diag ? wave : 3;        // frag t = keys [t*16, t*16+15]

        float ls = 0.f;
        unsigned int pw[4][2];
        #pragma unroll
        for (int t = 0; t < 4; ++t) {
            if (t <= tmax) {
                const int row = (t * 16 + col) * 64;
                const int sw = col & 7;
                bf16x8 ka0 = *(const bf16x8*)&Knc[row + (quad ^ sw) * 8];
                bf16x8 ka1 = *(const bf16x8*)&Knc[row + ((4 + quad) ^ sw) * 8];
                f32x4 c = {-16.f, -16.f, -16.f, -16.f};   // exp2 bias, free
                c = __builtin_amdgcn_mfma_f32_16x16x32_bf16(ka0, qa0, c, 0, 0, 0);
                c = __builtin_amdgcn_mfma_f32_16x16x32_bf16(ka1, qa1, c, 0, 0, 0);
                if (diag && t == wave) {
                    #pragma unroll
                    for (int r = 0; r < 4; ++r)
                        if (quad * 4 + r > col) c[r] = -1e30f;   // exp2 -> 0
                }
                const float p0 = exp2f(c[0]);
                const float p1 = exp2f(c[1]);
                const float p2 = exp2f(c[2]);
                const float p3 = exp2f(c[3]);
                ls += (p0 + p1) + (p2 + p3);
                pw[t][0] = pk2bf(p0, p1);
                pw[t][1] = pk2bf(p2, p3);
            } else {
                pw[t][0] = 0u; pw[t][1] = 0u;
            }
        }
        lsum += ls;

        // P -> LDS [query][key] (b64, conflict-free), read back as A-frags (per-wave)
        unsigned short* psb = &Ps[wave][col * LDK];
        #pragma unroll
        for (int t = 0; t < 4; ++t)
            *(uint2*)(psb + t * 16 + quad * 4) = make_uint2(pw[t][0], pw[t][1]);

        bf16x8 pa0 = *(const bf16x8*)(psb + quad * 8);        // keys 0..31
        bf16x8 pa1 = *(const bf16x8*)(psb + 32 + quad * 8);   // keys 32..63
        const bool hi = !(diag && wave < 2);                  // keys 32..63 all masked for w<2

        #pragma unroll
        for (int t = 0; t < 4; ++t) {
            const int row = (t * 16 + col) * 64;
            const int sw = col & 7;
            bf16x8 vb0 = *(const bf16x8*)&Ktc[row + (quad ^ sw) * 8];
            accO[t] = __builtin_amdgcn_mfma_f32_16x16x32_bf16(pa0, vb0, accO[t], 0, 0, 0);
            if (hi) {
                bf16x8 vb1 = *(const bf16x8*)&Ktc[row + ((4 + quad) ^ sw) * 8];
                accO[t] = __builtin_amdgcn_mfma_f32_16x16x32_bf16(pa1, vb1, accO[t], 0, 0, 0);
            }
        }
    }

    // epilogue: reduce l across quads once, then O /= l
    lsum += __shfl_xor(lsum, 16);
    lsum += __shfl_xor(lsum, 32);
    #pragma unroll
    for (int r = 0; r < 4; ++r) {
        const float lr = __shfl(lsum, (lane & 48) | (quad * 4 + r));
        const float inv = 1.f / lr;
        const size_t row = (size_t)b * 2048 + qtile * 64 + wave * 16 + quad * 4 + r;
        unsigned short* op = aout + row * 1024 + h * 64;
        op[col]      = f2bf(accO[0][r] * inv);
        op[16 + col] = f2bf(accO[1][r] * inv);
        op[32 + col] = f2bf(accO[2][r] * inv);
        op[48 + col] = f2bf(accO[3][r] * inv);
    }
}

// ---------- launch ----------
extern "C" void kernel_launch(void* const* d_in, const int* in_sizes, int n_in,
                              void* d_out, int out_size, void* d_ws, size_t ws_size,
                              hipStream_t stream) {
    (void)in_sizes; (void)n_in; (void)out_size; (void)ws_size;
    const float* x    = (const float*)d_in[0];   // [2,2048,1024]
    const float* Wqk  = (const float*)d_in[1];   // [1024,2048]
    const float* Wout = (const float*)d_in[2];   // [1024,1024]
    float* out = (float*)d_out;                  // [2,2048,1024] fp32

    unsigned short* xb     = (unsigned short*)d_ws;            // [4096][1024]
    unsigned short* Wqk_t  = xb     + (size_t)4096 * 1024;     // [2048][1024]
    unsigned short* Wout_t = Wqk_t  + (size_t)2048 * 1024;     // [1024][1024]
    unsigned short* qkb    = Wout_t + (size_t)1024 * 1024;     // [4096][2048]
    unsigned short* aoutb  = qkb    + (size_t)4096 * 2048;     // [4096][1024]
    unsigned short* kT     = xb;                               // [2048][2048] (x dead after GEMM1)

    cast_x_kernel<<<dim3(4096 * 1024 / (256 * 8)), dim3(256), 0, stream>>>(x, xb, 4096 * 1024);
    transpose_cast_kernel<<<dim3(32, 64), dim3(256), 0, stream>>>(Wqk, Wqk_t, 1024, 2048);
    transpose_cast_kernel<<<dim3(32, 32), dim3(256), 0, stream>>>(Wout, Wout_t, 1024, 1024);

    // qk = x @ W_qk -> bf16 [4096][2048]
    gemm128_kernel<true><<<dim3(32, 16), dim3(256), 0, stream>>>(
        xb, Wqk_t, (void*)qkb, 1024, 1024, 1024, 2048);

    // K^T per batch: [b*1024+f][token]
    ktrans_kernel<<<dim3(32, 16, 2), dim3(256), 0, stream>>>(qkb, kT);

    // causal MFMA flash attention -> bf16 [4096][1024]
    attn_v5_kernel<<<dim3(32, 32), dim3(256), 0, stream>>>(qkb, kT, aoutb);

    // out = attn_out @ W_out -> fp32
    gemm128_kernel<false><<<dim3(32, 8), dim3(256), 0, stream>>>(
        aoutb, Wout_t, (void*)out, 1024, 1024, 1024, 1024);
}